// Round 3
// baseline (287.563 us; speedup 1.0000x reference)
//
#include <hip/hip_runtime.h>

typedef __bf16 bf16;
typedef __bf16 bf16x8 __attribute__((ext_vector_type(8)));
typedef float  f32x4  __attribute__((ext_vector_type(4)));

#define VOC 65

// workspace layout (element offsets, bf16)
#define WS_WQ 0
#define WS_WK 16384
#define WS_WV 32768
#define WS_WO 49152
#define WS_W1 65536
#define WS_W2 196608
#define WS_WF 327680   // padded [80][32]

// ---------------- prep kernels: f32 -> bf16 transpose to [col][k] (k contiguous) ----------------
__global__ void transpose_f32bf16_k(const float* __restrict__ src, bf16* __restrict__ dst,
                                    int batch, int R, int C) {
  int i = blockIdx.x * blockDim.x + threadIdx.x;
  int total = batch * R * C;
  if (i >= total) return;
  int b = i / (R * C);
  int rc = i - b * (R * C);
  int r = rc / C;
  int c = rc - r * C;
  dst[(b * C + c) * R + r] = (bf16)src[i];   // [b][R][C] -> [b][C][R]
}

__global__ void prep_wf_k(const float* __restrict__ wf, bf16* __restrict__ dst) {
  int i = blockIdx.x * blockDim.x + threadIdx.x;  // 80*32
  if (i >= 80 * 32) return;
  int c = i >> 5, r = i & 31;
  dst[i] = (c < VOC) ? (bf16)wf[r * VOC + c] : (bf16)0.0f;  // [80 cols][32 k], cols 65..79 zero
}

// ---------------- fused transformer ----------------
struct __align__(16) SeqLds {
  bf16 h[16][40];    // activations [token][dim 0..31], pad 32..39
  bf16 q[16][72];    // q rows / attn-out bounce [token][64], pad 64..71
  bf16 k[16][72];
  bf16 vT[64][32];   // [vdim][key 0..15], keys 16..31 stay zero (K-pad for PV MFMA)
  bf16 p[16][32];    // [query][key 0..15], keys 16..31 stay zero
  bf16 mbuf[16][40]; // FFN relu bounce [token][32 of hid]
};

#define MFMA(a,b,c) __builtin_amdgcn_mfma_f32_16x16x32_bf16((a),(b),(c),0,0,0)

__global__ __launch_bounds__(128)
void xformer_k(const int* __restrict__ x, const float* __restrict__ emb, const float* __restrict__ pos,
               const float* __restrict__ bq, const float* __restrict__ bk, const float* __restrict__ bv,
               const float* __restrict__ bo, const float* __restrict__ ga, const float* __restrict__ ba,
               const float* __restrict__ b1, const float* __restrict__ b2,
               const float* __restrict__ gm, const float* __restrict__ bm,
               const float* __restrict__ bfin,
               const bf16* __restrict__ ws, float* __restrict__ out)
{
  __shared__ SeqLds sh[4];           // 4 seqs per block (2 waves x 2 seqs), 48 KB
  const int tid  = threadIdx.x;
  const int wv   = tid >> 6;
  const int lane = tid & 63;
  const int lo   = lane & 15;        // MFMA A-row / B-col / D-col index
  const int hi   = lane >> 4;        // 0..3 (k-group / D-row group)
  const int seq0 = blockIdx.x * 4 + wv * 2;

  const bf16* wqT = ws + WS_WQ;      // [l*4+h][64 col][32 k]
  const bf16* wkT = ws + WS_WK;
  const bf16* wvT = ws + WS_WV;
  const bf16* woT = ws + WS_WO;      // [l][32 col][256 k]
  const bf16* w1T = ws + WS_W1;      // [l][2048 col][32 k]
  const bf16* w2T = ws + WS_W2;      // [l][32 col][2048 k]
  const bf16* wfT = ws + WS_WF;      // [80 col][32 k]

  const f32x4 fz = {0.f, 0.f, 0.f, 0.f};

  // ---- zero-init ALL of LDS (pads become real zeros) ----
  {
    uint32_t* z = (uint32_t*)&sh[0];
    const int nwords = (int)(sizeof(SeqLds) * 4 / 4);
    for (int i = tid; i < nwords; i += 128) z[i] = 0u;
  }
  __syncthreads();

  // ---- embedding: h = (emb[x] + pos) * sqrt(32) ----
  for (int si = 0; si < 2; ++si) {
    SeqLds& L = sh[wv*2+si];
    int s = seq0 + si;
    #pragma unroll
    for (int i = 0; i < 8; ++i) {
      int idx = i * 64 + lane;       // 0..511 over [16][32]
      int r = idx >> 5, c = idx & 31;
      int id = x[s * 16 + r];
      id = id < 0 ? 0 : (id >= VOC ? VOC - 1 : id);
      float v = (emb[id * 32 + c] + pos[r * 32 + c]) * 5.656854249492381f;
      L.h[r][c] = (bf16)v;
    }
  }
  __syncthreads();

  for (int l = 0; l < 2; ++l) {
    // ================= attention =================
    f32x4 accO[2][2] = {{fz,fz},{fz,fz}};   // [seq][n-tile] out-proj accumulator
    for (int hh = 0; hh < 4; ++hh) {
      // ---- stage A: q,k,v projections [16,32]@[32,64] -> q,k,vT ----
      #pragma unroll
      for (int nt = 0; nt < 4; ++nt) {
        int colh = nt * 16 + lo;                         // 0..63 within head
        int wofs = ((l * 4 + hh) * 64 + colh) * 32 + hi * 8;
        bf16x8 wq8 = *(const bf16x8*)(wqT + wofs);
        bf16x8 wk8 = *(const bf16x8*)(wkT + wofs);
        bf16x8 wv8 = *(const bf16x8*)(wvT + wofs);
        float bqv = bq[(l*4+hh)*64 + colh];
        float bkv = bk[(l*4+hh)*64 + colh];
        float bvv = bv[(l*4+hh)*64 + colh];
        #pragma unroll
        for (int si = 0; si < 2; ++si) {
          SeqLds& L = sh[wv*2+si];
          bf16x8 a = *(const bf16x8*)(&L.h[lo][hi*8]);
          f32x4 dq = MFMA(a, wq8, fz);
          f32x4 dk = MFMA(a, wk8, fz);
          f32x4 dv = MFMA(a, wv8, fz);
          #pragma unroll
          for (int r = 0; r < 4; ++r) {
            int row = hi*4 + r;                          // token
            L.q[row][colh] = (bf16)(dq[r] + bqv);
            L.k[row][colh] = (bf16)(dk[r] + bkv);
            L.vT[colh][row] = (bf16)(dv[r] + bvv);       // transposed for PV B-frag
          }
        }
      }
      __syncthreads();
      // ---- stage B: scores + softmax -> p ----
      #pragma unroll
      for (int si = 0; si < 2; ++si) {
        SeqLds& L = sh[wv*2+si];
        f32x4 sf = fz;
        #pragma unroll
        for (int kk = 0; kk < 2; ++kk) {
          bf16x8 aq  = *(const bf16x8*)(&L.q[lo][kk*32 + hi*8]);   // A row = query = lo
          bf16x8 bk8 = *(const bf16x8*)(&L.k[lo][kk*32 + hi*8]);   // B col = key = lo
          sf = MFMA(aq, bk8, sf);
        }
        // D: col=lo=key, row=hi*4+r=query
        #pragma unroll
        for (int r = 0; r < 4; ++r) {
          int row = hi*4 + r;
          float v0 = (lo <= row) ? sf[r] * 0.125f : -30000.0f;   // causal mask
          float mx = v0;
          mx = fmaxf(mx, __shfl_xor(mx, 1));
          mx = fmaxf(mx, __shfl_xor(mx, 2));
          mx = fmaxf(mx, __shfl_xor(mx, 4));
          mx = fmaxf(mx, __shfl_xor(mx, 8));
          float e = __expf(v0 - mx);
          float sm = e;
          sm += __shfl_xor(sm, 1);
          sm += __shfl_xor(sm, 2);
          sm += __shfl_xor(sm, 4);
          sm += __shfl_xor(sm, 8);
          L.p[row][lo] = (bf16)(e / sm);
        }
      }
      __syncthreads();
      // ---- stage C: o = p @ v (K=16 zero-padded to 32; pads are real zeros) ----
      #pragma unroll
      for (int si = 0; si < 2; ++si) {
        SeqLds& L = sh[wv*2+si];
        bf16x8 ap = *(const bf16x8*)(&L.p[lo][hi*8]);    // A row = query = lo
        #pragma unroll
        for (int nt = 0; nt < 4; ++nt) {
          bf16x8 bv8 = *(const bf16x8*)(&L.vT[nt*16+lo][hi*8]);  // B col = vdim
          f32x4 o = MFMA(ap, bv8, fz);
          #pragma unroll
          for (int r = 0; r < 4; ++r) L.q[hi*4+r][nt*16+lo] = (bf16)o[r];  // q reused as o
        }
      }
      __syncthreads();
      // ---- stage D: out-proj accumulate o_head[16,64] @ Wo[hh*64.., :32] ----
      #pragma unroll
      for (int si = 0; si < 2; ++si) {
        SeqLds& L = sh[wv*2+si];
        #pragma unroll
        for (int kk = 0; kk < 2; ++kk) {
          bf16x8 ao = *(const bf16x8*)(&L.q[lo][kk*32 + hi*8]);
          #pragma unroll
          for (int n2 = 0; n2 < 2; ++n2) {
            bf16x8 bw = *(const bf16x8*)(woT + (l*32 + n2*16 + lo)*256 + hh*64 + kk*32 + hi*8);
            accO[si][n2] = MFMA(ao, bw, accO[si][n2]);
          }
        }
      }
      __syncthreads();
    }
    // ---- + bo + residual + LN(ga,ba) -> h ----
    #pragma unroll
    for (int si = 0; si < 2; ++si) {
      SeqLds& L = sh[wv*2+si];
      float g0 = ga[l*32 + lo], g1 = ga[l*32 + 16 + lo];
      float e0 = ba[l*32 + lo], e1 = ba[l*32 + 16 + lo];
      float o0 = bo[l*32 + lo], o1 = bo[l*32 + 16 + lo];
      #pragma unroll
      for (int r = 0; r < 4; ++r) {
        int row = hi*4 + r;
        float v0 = accO[si][0][r] + o0 + (float)L.h[row][lo];
        float v1 = accO[si][1][r] + o1 + (float)L.h[row][16+lo];
        float s1 = v0 + v1, s2 = v0*v0 + v1*v1;
        s1 += __shfl_xor(s1, 1); s2 += __shfl_xor(s2, 1);
        s1 += __shfl_xor(s1, 2); s2 += __shfl_xor(s2, 2);
        s1 += __shfl_xor(s1, 4); s2 += __shfl_xor(s2, 4);
        s1 += __shfl_xor(s1, 8); s2 += __shfl_xor(s2, 8);
        float mean = s1 * (1.f/32.f);
        float var  = s2 * (1.f/32.f) - mean*mean;
        float rs   = rsqrtf(fabsf(var) + 1e-5f);
        L.h[row][lo]    = (bf16)((v0-mean)*rs*g0 + e0);
        L.h[row][16+lo] = (bf16)((v1-mean)*rs*g1 + e1);
      }
    }
    __syncthreads();
    // ================= FFN =================
    f32x4 acc2[2][2] = {{fz,fz},{fz,fz}};
    bf16x8 ah[2];
    #pragma unroll
    for (int si = 0; si < 2; ++si) ah[si] = *(const bf16x8*)(&sh[wv*2+si].h[lo][hi*8]);
    for (int kk = 0; kk < 64; ++kk) {        // 64 k-steps of 32 hidden units
      #pragma unroll
      for (int t = 0; t < 2; ++t) {
        int col = (kk*2 + t)*16 + lo;        // hidden unit
        bf16x8 w1f = *(const bf16x8*)(w1T + (l*2048 + col)*32 + hi*8);
        float bb = b1[l*2048 + col];
        #pragma unroll
        for (int si = 0; si < 2; ++si) {
          SeqLds& L = sh[wv*2+si];
          f32x4 d = MFMA(ah[si], w1f, fz);
          #pragma unroll
          for (int r = 0; r < 4; ++r) {
            float m = d[r] + bb;
            L.mbuf[hi*4+r][t*16+lo] = (bf16)(m > 0.f ? m : 0.f);
          }
        }
      }
      __syncthreads();
      #pragma unroll
      for (int si = 0; si < 2; ++si) {
        SeqLds& L = sh[wv*2+si];
        bf16x8 am = *(const bf16x8*)(&L.mbuf[lo][hi*8]);
        #pragma unroll
        for (int n2 = 0; n2 < 2; ++n2) {
          bf16x8 w2f = *(const bf16x8*)(w2T + (l*32 + n2*16 + lo)*2048 + kk*32 + hi*8);
          acc2[si][n2] = MFMA(am, w2f, acc2[si][n2]);
        }
      }
      __syncthreads();
    }
    // ---- + b2 + residual + LN(gm,bm) -> h ----
    #pragma unroll
    for (int si = 0; si < 2; ++si) {
      SeqLds& L = sh[wv*2+si];
      float g0 = gm[l*32 + lo], g1 = gm[l*32 + 16 + lo];
      float e0 = bm[l*32 + lo], e1 = bm[l*32 + 16 + lo];
      float c0 = b2[l*32 + lo], c1 = b2[l*32 + 16 + lo];
      #pragma unroll
      for (int r = 0; r < 4; ++r) {
        int row = hi*4 + r;
        float v0 = acc2[si][0][r] + c0 + (float)L.h[row][lo];
        float v1 = acc2[si][1][r] + c1 + (float)L.h[row][16+lo];
        float s1 = v0 + v1, s2 = v0*v0 + v1*v1;
        s1 += __shfl_xor(s1, 1); s2 += __shfl_xor(s2, 1);
        s1 += __shfl_xor(s1, 2); s2 += __shfl_xor(s2, 2);
        s1 += __shfl_xor(s1, 4); s2 += __shfl_xor(s2, 4);
        s1 += __shfl_xor(s1, 8); s2 += __shfl_xor(s2, 8);
        float mean = s1 * (1.f/32.f);
        float var  = s2 * (1.f/32.f) - mean*mean;
        float rs   = rsqrtf(fabsf(var) + 1e-5f);
        L.h[row][lo]    = (bf16)((v0-mean)*rs*g0 + e0);
        L.h[row][16+lo] = (bf16)((v1-mean)*rs*g1 + e1);
      }
    }
    __syncthreads();
  }

  // ---- final classifier: h @ Wf + bf -> out [s,16,65] (f32) ----
  #pragma unroll
  for (int si = 0; si < 2; ++si) {
    SeqLds& L = sh[wv*2+si];
    int s = seq0 + si;
    bf16x8 a = *(const bf16x8*)(&L.h[lo][hi*8]);
    #pragma unroll
    for (int nt = 0; nt < 5; ++nt) {
      bf16x8 w = *(const bf16x8*)(wfT + (nt*16+lo)*32 + hi*8);
      f32x4 d = MFMA(a, w, fz);
      int col = nt*16 + lo;
      if (col < VOC) {
        float bb = bfin[col];
        #pragma unroll
        for (int r = 0; r < 4; ++r)
          out[(s*16 + hi*4 + r)*VOC + col] = d[r] + bb;
      }
    }
  }
}

extern "C" void kernel_launch(void* const* d_in, const int* in_sizes, int n_in,
                              void* d_out, int out_size, void* d_ws, size_t ws_size,
                              hipStream_t stream) {
  const int*   x   = (const int*)d_in[0];
  const float* emb = (const float*)d_in[1];
  const float* pos = (const float*)d_in[2];
  const float* Wq  = (const float*)d_in[3];
  const float* bq  = (const float*)d_in[4];
  const float* Wk  = (const float*)d_in[5];
  const float* bk  = (const float*)d_in[6];
  const float* Wv  = (const float*)d_in[7];
  const float* bv  = (const float*)d_in[8];
  const float* Wo  = (const float*)d_in[9];
  const float* bo  = (const float*)d_in[10];
  const float* ga  = (const float*)d_in[11];
  const float* ba  = (const float*)d_in[12];
  const float* W1  = (const float*)d_in[13];
  const float* b1  = (const float*)d_in[14];
  const float* W2  = (const float*)d_in[15];
  const float* b2  = (const float*)d_in[16];
  const float* gm  = (const float*)d_in[17];
  const float* bm  = (const float*)d_in[18];
  const float* Wf  = (const float*)d_in[19];
  const float* bfin= (const float*)d_in[20];

  bf16* ws = (bf16*)d_ws;

  // transpose weights (f32 -> bf16) into MFMA-B layout [col][k] (k contiguous)
  transpose_f32bf16_k<<<64, 256, 0, stream>>>(Wq, ws + WS_WQ, 8, 32, 64);
  transpose_f32bf16_k<<<64, 256, 0, stream>>>(Wk, ws + WS_WK, 8, 32, 64);
  transpose_f32bf16_k<<<64, 256, 0, stream>>>(Wv, ws + WS_WV, 8, 32, 64);
  transpose_f32bf16_k<<<64, 256, 0, stream>>>(Wo, ws + WS_WO, 2, 256, 32);
  transpose_f32bf16_k<<<512, 256, 0, stream>>>(W1, ws + WS_W1, 2, 32, 2048);
  transpose_f32bf16_k<<<512, 256, 0, stream>>>(W2, ws + WS_W2, 2, 2048, 32);
  prep_wf_k<<<10, 256, 0, stream>>>(Wf, ws + WS_WF);

  // fused transformer: 1024 blocks x 128 threads, 4 seqs/block
  xformer_k<<<1024, 128, 0, stream>>>(x, emb, pos, bq, bk, bv, bo, ga, ba,
                                      b1, b2, gm, bm, bfin,
                                      ws, (float*)d_out);
}

// Round 7
// 163.634 us; speedup vs baseline: 1.7574x; 1.7574x over previous
//
#include <hip/hip_runtime.h>

typedef __bf16 bf16;
typedef __bf16 bf16x8 __attribute__((ext_vector_type(8)));
typedef float  f32x4  __attribute__((ext_vector_type(4)));

#define VOC 65

// workspace layout (element offsets, bf16)
#define WS_WQ 0
#define WS_WK 16384
#define WS_WV 32768
#define WS_WO 49152
#define WS_W1 65536
#define WS_W2 196608
#define WS_WF 327680   // padded [80][32]

// ---------------- prep kernels: f32 -> bf16 transpose to [col][k] (k contiguous) ----------------
__global__ void transpose_f32bf16_k(const float* __restrict__ src, bf16* __restrict__ dst,
                                    int batch, int R, int C) {
  int i = blockIdx.x * blockDim.x + threadIdx.x;
  int total = batch * R * C;
  if (i >= total) return;
  int b = i / (R * C);
  int rc = i - b * (R * C);
  int r = rc / C;
  int c = rc - r * C;
  dst[(b * C + c) * R + r] = (bf16)src[i];   // [b][R][C] -> [b][C][R]
}

__global__ void prep_wf_k(const float* __restrict__ wf, bf16* __restrict__ dst) {
  int i = blockIdx.x * blockDim.x + threadIdx.x;  // 80*32
  if (i >= 80 * 32) return;
  int c = i >> 5, r = i & 31;
  dst[i] = (c < VOC) ? (bf16)wf[r * VOC + c] : (bf16)0.0f;  // [80 cols][32 k], cols 65..79 zero
}

// ---------------- fused transformer ----------------
// R3-proven orientation. Padding-only conflict fixes (vT/p stride 48B),
// union reclaims LDS (38.9 KB/block -> 4 blocks/CU), FFN 1 barrier/iter.
struct __align__(16) SeqLds {
  bf16 h[16][40];    // activations [token][dim 0..31], pad 32..39
  bf16 q[16][72];    // q rows / attn-out bounce [token][64], pad 64..71
  bf16 k[16][72];
  union {
    struct {
      bf16 vT[64][24];  // [vdim][key 0..15], stride 48B (2-way banks)
      bf16 p [16][24];  // [query][key 0..15], stride 48B
    } att;
    bf16 mbuf[16][72];  // FFN relu bounce, two 32-col parity windows
  } u;
};                      // 9728 B/seq, 38912 B/block

#define MFMA(a,b,c) __builtin_amdgcn_mfma_f32_16x16x32_bf16((a),(b),(c),0,0,0)

__global__ __launch_bounds__(128)
void xformer_k(const int* __restrict__ x, const float* __restrict__ emb, const float* __restrict__ pos,
               const float* __restrict__ bq, const float* __restrict__ bk, const float* __restrict__ bv,
               const float* __restrict__ bo, const float* __restrict__ ga, const float* __restrict__ ba,
               const float* __restrict__ b1, const float* __restrict__ b2,
               const float* __restrict__ gm, const float* __restrict__ bm,
               const float* __restrict__ bfin,
               const bf16* __restrict__ ws, float* __restrict__ out)
{
  __shared__ SeqLds sh[4];           // 4 seqs per block (2 waves x 2 seqs)
  const int tid  = threadIdx.x;
  const int wv   = tid >> 6;
  const int lane = tid & 63;
  const int lo   = lane & 15;        // MFMA A-row / B-col / D-col index
  const int hi   = lane >> 4;        // 0..3 (k-group / D-row group)
  const int seq0 = blockIdx.x * 4 + wv * 2;

  const bf16* wqT = ws + WS_WQ;      // [l*4+h][64 col][32 k]
  const bf16* wkT = ws + WS_WK;
  const bf16* wvT = ws + WS_WV;
  const bf16* woT = ws + WS_WO;      // [l][32 col][256 k]
  const bf16* w1T = ws + WS_W1;      // [l][2048 col][32 k]
  const bf16* w2T = ws + WS_W2;      // [l][32 col][2048 k]
  const bf16* wfT = ws + WS_WF;      // [80 col][32 k]

  const f32x4 fz = {0.f, 0.f, 0.f, 0.f};
  const bf16x8 bz8 = {(bf16)0.f,(bf16)0.f,(bf16)0.f,(bf16)0.f,
                      (bf16)0.f,(bf16)0.f,(bf16)0.f,(bf16)0.f};

  // ---- embedding: h = (emb[x] + pos) * sqrt(32) ---- (R3 verbatim)
  for (int si = 0; si < 2; ++si) {
    SeqLds& L = sh[wv*2+si];
    int s = seq0 + si;
    #pragma unroll
    for (int i = 0; i < 8; ++i) {
      int idx = i * 64 + lane;       // 0..511 over [16][32]
      int r = idx >> 5, c = idx & 31;
      int id = x[s * 16 + r];
      id = id < 0 ? 0 : (id >= VOC ? VOC - 1 : id);
      float v = (emb[id * 32 + c] + pos[r * 32 + c]) * 5.656854249492381f;
      L.h[r][c] = (bf16)v;
    }
  }
  __syncthreads();

  for (int l = 0; l < 2; ++l) {
    // ================= attention ================= (R3 verbatim except vT/p paths)
    f32x4 accO[2][2] = {{fz,fz},{fz,fz}};   // [seq][n-tile] out-proj accumulator
    for (int hh = 0; hh < 4; ++hh) {
      // ---- stage A: q,k,v projections [16,32]@[32,64] -> q,k,vT ----
      #pragma unroll
      for (int nt = 0; nt < 4; ++nt) {
        int colh = nt * 16 + lo;                         // 0..63 within head
        int wofs = ((l * 4 + hh) * 64 + colh) * 32 + hi * 8;
        bf16x8 wq8 = *(const bf16x8*)(wqT + wofs);
        bf16x8 wk8 = *(const bf16x8*)(wkT + wofs);
        bf16x8 wv8 = *(const bf16x8*)(wvT + wofs);
        float bqv = bq[(l*4+hh)*64 + colh];
        float bkv = bk[(l*4+hh)*64 + colh];
        float bvv = bv[(l*4+hh)*64 + colh];
        #pragma unroll
        for (int si = 0; si < 2; ++si) {
          SeqLds& L = sh[wv*2+si];
          bf16x8 a = *(const bf16x8*)(&L.h[lo][hi*8]);
          f32x4 dq = MFMA(a, wq8, fz);
          f32x4 dk = MFMA(a, wk8, fz);
          f32x4 dv = MFMA(a, wv8, fz);
          #pragma unroll
          for (int r = 0; r < 4; ++r) {
            int row = hi*4 + r;                          // token
            L.q[row][colh] = (bf16)(dq[r] + bqv);
            L.k[row][colh] = (bf16)(dk[r] + bkv);
            L.u.att.vT[colh][row] = (bf16)(dv[r] + bvv); // transposed for PV B-frag
          }
        }
      }
      __syncthreads();                // A writes -> B reads
      // ---- stage B: scores + softmax -> p ----
      #pragma unroll
      for (int si = 0; si < 2; ++si) {
        SeqLds& L = sh[wv*2+si];
        f32x4 sf = fz;
        #pragma unroll
        for (int kk = 0; kk < 2; ++kk) {
          bf16x8 aq  = *(const bf16x8*)(&L.q[lo][kk*32 + hi*8]);   // A row = query = lo
          bf16x8 bk8 = *(const bf16x8*)(&L.k[lo][kk*32 + hi*8]);   // B col = key = lo
          sf = MFMA(aq, bk8, sf);
        }
        // D: col=lo=key, row=hi*4+r=query
        #pragma unroll
        for (int r = 0; r < 4; ++r) {
          int row = hi*4 + r;
          float v0 = (lo <= row) ? sf[r] * 0.125f : -30000.0f;   // causal mask
          float mx = v0;
          mx = fmaxf(mx, __shfl_xor(mx, 1));
          mx = fmaxf(mx, __shfl_xor(mx, 2));
          mx = fmaxf(mx, __shfl_xor(mx, 4));
          mx = fmaxf(mx, __shfl_xor(mx, 8));
          float e = __expf(v0 - mx);
          float sm = e;
          sm += __shfl_xor(sm, 1);
          sm += __shfl_xor(sm, 2);
          sm += __shfl_xor(sm, 4);
          sm += __shfl_xor(sm, 8);
          L.u.att.p[row][lo] = (bf16)(e / sm);
        }
      }
      __syncthreads();                // B writes -> C reads
      // ---- stage C: o = p @ v (K=16, zero-padded to 32 via register zeros) ----
      #pragma unroll
      for (int si = 0; si < 2; ++si) {
        SeqLds& L = sh[wv*2+si];
        bf16x8 ap = (hi < 2) ? *(const bf16x8*)(&L.u.att.p[lo][hi*8]) : bz8;
        #pragma unroll
        for (int nt = 0; nt < 4; ++nt) {
          bf16x8 bv8 = (hi < 2) ? *(const bf16x8*)(&L.u.att.vT[nt*16+lo][hi*8]) : bz8;
          f32x4 o = MFMA(ap, bv8, fz);
          #pragma unroll
          for (int r = 0; r < 4; ++r) L.q[hi*4+r][nt*16+lo] = (bf16)o[r];  // q reused as o
        }
      }
      __syncthreads();                // C writes -> D reads
      // ---- stage D: out-proj accumulate o_head[16,64] @ Wo[hh*64.., :32] ----
      #pragma unroll
      for (int si = 0; si < 2; ++si) {
        SeqLds& L = sh[wv*2+si];
        #pragma unroll
        for (int kk = 0; kk < 2; ++kk) {
          bf16x8 ao = *(const bf16x8*)(&L.q[lo][kk*32 + hi*8]);
          #pragma unroll
          for (int n2 = 0; n2 < 2; ++n2) {
            bf16x8 bw = *(const bf16x8*)(woT + (l*32 + n2*16 + lo)*256 + hh*64 + kk*32 + hi*8);
            accO[si][n2] = MFMA(ao, bw, accO[si][n2]);
          }
        }
      }
      __syncthreads();                // D reads -> next-head A writes (WAR)
    }
    // ---- + bo + residual + LN(ga,ba) -> h ---- (R3 verbatim)
    #pragma unroll
    for (int si = 0; si < 2; ++si) {
      SeqLds& L = sh[wv*2+si];
      float g0 = ga[l*32 + lo], g1 = ga[l*32 + 16 + lo];
      float e0 = ba[l*32 + lo], e1 = ba[l*32 + 16 + lo];
      float o0 = bo[l*32 + lo], o1 = bo[l*32 + 16 + lo];
      #pragma unroll
      for (int r = 0; r < 4; ++r) {
        int row = hi*4 + r;
        float v0 = accO[si][0][r] + o0 + (float)L.h[row][lo];
        float v1 = accO[si][1][r] + o1 + (float)L.h[row][16+lo];
        float s1 = v0 + v1, s2 = v0*v0 + v1*v1;
        s1 += __shfl_xor(s1, 1); s2 += __shfl_xor(s2, 1);
        s1 += __shfl_xor(s1, 2); s2 += __shfl_xor(s2, 2);
        s1 += __shfl_xor(s1, 4); s2 += __shfl_xor(s2, 4);
        s1 += __shfl_xor(s1, 8); s2 += __shfl_xor(s2, 8);
        float mean = s1 * (1.f/32.f);
        float var  = s2 * (1.f/32.f) - mean*mean;
        float rs   = rsqrtf(fabsf(var) + 1e-5f);
        L.h[row][lo]    = (bf16)((v0-mean)*rs*g0 + e0);
        L.h[row][16+lo] = (bf16)((v1-mean)*rs*g1 + e1);
      }
    }
    __syncthreads();
    // ================= FFN ================= (parity window: 1 barrier/iter + weight prefetch)
    f32x4 acc2[2][2] = {{fz,fz},{fz,fz}};
    bf16x8 ah[2];
    #pragma unroll
    for (int si = 0; si < 2; ++si) ah[si] = *(const bf16x8*)(&sh[wv*2+si].h[lo][hi*8]);
    const bf16* w1l = w1T + l*65536;
    const bf16* w2l = w2T + l*65536;
    const float* b1l = b1 + l*2048;
    // preload kk=0 weights
    bf16x8 w1c0 = *(const bf16x8*)(w1l + (lo)*32 + hi*8);
    bf16x8 w1c1 = *(const bf16x8*)(w1l + (16 + lo)*32 + hi*8);
    bf16x8 w2c0 = *(const bf16x8*)(w2l + (lo)*2048 + hi*8);
    bf16x8 w2c1 = *(const bf16x8*)(w2l + (16 + lo)*2048 + hi*8);
    for (int kk = 0; kk < 64; ++kk) {
      const int w = (kk & 1) * 32;    // parity window in mbuf
      // MFMA1 (hidden) + relu, store into window w
      {
        float bb0 = b1l[kk*32 + lo];
        float bb1 = b1l[kk*32 + 16 + lo];
        #pragma unroll
        for (int si = 0; si < 2; ++si) {
          SeqLds& L = sh[wv*2+si];
          f32x4 d0 = MFMA(ah[si], w1c0, fz);
          f32x4 d1 = MFMA(ah[si], w1c1, fz);
          #pragma unroll
          for (int r = 0; r < 4; ++r) {
            float m0 = d0[r] + bb0;
            float m1 = d1[r] + bb1;
            L.u.mbuf[hi*4+r][w + lo]      = (bf16)(m0 > 0.f ? m0 : 0.f);
            L.u.mbuf[hi*4+r][w + 16 + lo] = (bf16)(m1 > 0.f ? m1 : 0.f);
          }
        }
      }
      // prefetch next-iteration weights (kn=kk+1, clamped cyclically; extra regs unused at kk=63)
      const int kn = (kk + 1) & 63;
      bf16x8 w1n0 = *(const bf16x8*)(w1l + (kn*32 + lo)*32 + hi*8);
      bf16x8 w1n1 = *(const bf16x8*)(w1l + (kn*32 + 16 + lo)*32 + hi*8);
      bf16x8 w2n0 = *(const bf16x8*)(w2l + (lo)*2048 + kn*32 + hi*8);
      bf16x8 w2n1 = *(const bf16x8*)(w2l + (16 + lo)*2048 + kn*32 + hi*8);
      __syncthreads();                // m writes -> mf reads (single barrier per iter)
      #pragma unroll
      for (int si = 0; si < 2; ++si) {
        bf16x8 am = *(const bf16x8*)(&sh[wv*2+si].u.mbuf[lo][w + hi*8]);
        acc2[si][0] = MFMA(am, w2c0, acc2[si][0]);
        acc2[si][1] = MFMA(am, w2c1, acc2[si][1]);
      }
      w1c0 = w1n0; w1c1 = w1n1; w2c0 = w2n0; w2c1 = w2n1;
    }
    __syncthreads();
    // ---- + b2 + residual + LN(gm,bm) -> h ---- (R3 verbatim)
    #pragma unroll
    for (int si = 0; si < 2; ++si) {
      SeqLds& L = sh[wv*2+si];
      float g0 = gm[l*32 + lo], g1 = gm[l*32 + 16 + lo];
      float e0 = bm[l*32 + lo], e1 = bm[l*32 + 16 + lo];
      float c0 = b2[l*32 + lo], c1 = b2[l*32 + 16 + lo];
      #pragma unroll
      for (int r = 0; r < 4; ++r) {
        int row = hi*4 + r;
        float v0 = acc2[si][0][r] + c0 + (float)L.h[row][lo];
        float v1 = acc2[si][1][r] + c1 + (float)L.h[row][16+lo];
        float s1 = v0 + v1, s2 = v0*v0 + v1*v1;
        s1 += __shfl_xor(s1, 1); s2 += __shfl_xor(s2, 1);
        s1 += __shfl_xor(s1, 2); s2 += __shfl_xor(s2, 2);
        s1 += __shfl_xor(s1, 4); s2 += __shfl_xor(s2, 4);
        s1 += __shfl_xor(s1, 8); s2 += __shfl_xor(s2, 8);
        float mean = s1 * (1.f/32.f);
        float var  = s2 * (1.f/32.f) - mean*mean;
        float rs   = rsqrtf(fabsf(var) + 1e-5f);
        L.h[row][lo]    = (bf16)((v0-mean)*rs*g0 + e0);
        L.h[row][16+lo] = (bf16)((v1-mean)*rs*g1 + e1);
      }
    }
    __syncthreads();
  }

  // ---- final classifier: h @ Wf + bf -> out [s,16,65] (f32) ---- (R3 verbatim)
  #pragma unroll
  for (int si = 0; si < 2; ++si) {
    SeqLds& L = sh[wv*2+si];
    int s = seq0 + si;
    bf16x8 a = *(const bf16x8*)(&L.h[lo][hi*8]);
    #pragma unroll
    for (int nt = 0; nt < 5; ++nt) {
      bf16x8 w = *(const bf16x8*)(wfT + (nt*16+lo)*32 + hi*8);
      f32x4 d = MFMA(a, w, fz);
      int col = nt*16 + lo;
      if (col < VOC) {
        float bb = bfin[col];
        #pragma unroll
        for (int r = 0; r < 4; ++r)
          out[(s*16 + hi*4 + r)*VOC + col] = d[r] + bb;
      }
    }
  }
}

extern "C" void kernel_launch(void* const* d_in, const int* in_sizes, int n_in,
                              void* d_out, int out_size, void* d_ws, size_t ws_size,
                              hipStream_t stream) {
  const int*   x   = (const int*)d_in[0];
  const float* emb = (const float*)d_in[1];
  const float* pos = (const float*)d_in[2];
  const float* Wq  = (const float*)d_in[3];
  const float* bq  = (const float*)d_in[4];
  const float* Wk  = (const float*)d_in[5];
  const float* bk  = (const float*)d_in[6];
  const float* Wv  = (const float*)d_in[7];
  const float* bv  = (const float*)d_in[8];
  const float* Wo  = (const float*)d_in[9];
  const float* bo  = (const float*)d_in[10];
  const float* ga  = (const float*)d_in[11];
  const float* ba  = (const float*)d_in[12];
  const float* W1  = (const float*)d_in[13];
  const float* b1  = (const float*)d_in[14];
  const float* W2  = (const float*)d_in[15];
  const float* b2  = (const float*)d_in[16];
  const float* gm  = (const float*)d_in[17];
  const float* bm  = (const float*)d_in[18];
  const float* Wf  = (const float*)d_in[19];
  const float* bfin= (const float*)d_in[20];

  bf16* ws = (bf16*)d_ws;

  // transpose weights (f32 -> bf16) into MFMA-B layout [col][k] (k contiguous)
  transpose_f32bf16_k<<<64, 256, 0, stream>>>(Wq, ws + WS_WQ, 8, 32, 64);
  transpose_f32bf16_k<<<64, 256, 0, stream>>>(Wk, ws + WS_WK, 8, 32, 64);
  transpose_f32bf16_k<<<64, 256, 0, stream>>>(Wv, ws + WS_WV, 8, 32, 64);
  transpose_f32bf16_k<<<64, 256, 0, stream>>>(Wo, ws + WS_WO, 2, 256, 32);
  transpose_f32bf16_k<<<512, 256, 0, stream>>>(W1, ws + WS_W1, 2, 32, 2048);
  transpose_f32bf16_k<<<512, 256, 0, stream>>>(W2, ws + WS_W2, 2, 2048, 32);
  prep_wf_k<<<10, 256, 0, stream>>>(Wf, ws + WS_WF);

  // fused transformer: 1024 blocks x 128 threads, 4 seqs/block
  xformer_k<<<1024, 128, 0, stream>>>(x, emb, pos, bq, bk, bv, bo, ga, ba,
                                      b1, b2, gm, bm, bfin,
                                      ws, (float*)d_out);
}